// Round 6
// baseline (159.379 us; speedup 1.0000x reference)
//
#include <hip/hip_runtime.h>
#include <math.h>

// MOTIP criterion, single fused kernel, TWO frames per 512-thread block:
// waves 0-3 process frame A, waves 4-7 frame B -> 2 independent latency
// chains per SIMD (kernel was exposed-latency-bound at 1 wave/SIMD).
// Cost matrix stored fp16 so 2 frames fit in 64 KB static LDS.
// F=128 frames, N=300 preds, M=32 targets, C=2 classes, K1=512 id classes.

constexpr int F_FRAMES = 128;
constexpr int N_PRED   = 300;
constexpr int M_TGT    = 32;
constexpr int K_ID     = 512;
constexpr int NSLOT    = 5;     // ceil(300/64) for the solver wave
constexpr int PITCH    = 304;   // fp16 cost row pitch
constexpr int FPB      = 2;     // frames per block
constexpr int NBLOCKS  = F_FRAMES / FPB;   // 64

using f16 = _Float16;

// ---------- 5-element register-array dynamic access ----------
__device__ __forceinline__ int sel5i(const int a[NSLOT], int s) {
    int r = a[0];
    r = (s == 1) ? a[1] : r;
    r = (s == 2) ? a[2] : r;
    r = (s == 3) ? a[3] : r;
    r = (s == 4) ? a[4] : r;
    return r;
}
__device__ __forceinline__ float sel5f(const float a[NSLOT], int s) {
    float r = a[0];
    r = (s == 1) ? a[1] : r;
    r = (s == 2) ? a[2] : r;
    r = (s == 3) ? a[3] : r;
    r = (s == 4) ? a[4] : r;
    return r;
}
__device__ __forceinline__ void set5i(int a[NSLOT], int s, int val) {
    if (s == 0) a[0] = val;
    if (s == 1) a[1] = val;
    if (s == 2) a[2] = val;
    if (s == 3) a[3] = val;
    if (s == 4) a[4] = val;
}
// monotone float -> uint (order-preserving)
__device__ __forceinline__ unsigned mono32(float x) {
    unsigned b = __float_as_uint(x);
    return b ^ ((b & 0x80000000u) ? 0xFFFFFFFFu : 0x80000000u);
}

__global__ __launch_bounds__(512) void motip_fused_kernel(
    const float* __restrict__ pl,      // [F,N,2]
    const float* __restrict__ pb,      // [F,N,4]
    const float* __restrict__ il,      // [F,N,K]
    const int*   __restrict__ labels,  // [F,M]
    const float* __restrict__ tb,      // [F,M,4]
    const int*   __restrict__ tids,    // [F,M]
    float* __restrict__ frame_part,    // [F,4] in ws
    int*   __restrict__ counter,       // zeroed by memsetAsync
    float* __restrict__ out)           // [5]
{
    const int tid  = threadIdx.x;
    const int fl   = tid >> 8;          // frame-local 0/1
    const int t    = tid & 255;         // thread within frame group
    const int lane = tid & 63;
    const int w4   = (tid >> 6) & 3;    // wave role within frame group
    const int f    = blockIdx.x * FPB + fl;

    __shared__ f16   s_cost[FPB][M_TGT * PITCH];   // 2 x 19456 B
    __shared__ float s_pbox[FPB][N_PRED][4];       // pred cxcywh
    __shared__ int   s_claim[FPB][N_PRED];
    __shared__ float s_tgt[FPB][M_TGT][9];         // cx,cy,w,h,x0,y0,x1,y1,area
    __shared__ int   s_lab[FPB][M_TGT];
    __shared__ int   s_tid[FPB][M_TGT];
    __shared__ float s_rowval[FPB][M_TGT];
    __shared__ int   s_rowarg[FPB][M_TGT];
    __shared__ int   s_col4row[FPB][M_TGT];
    __shared__ float s_lse[FPB][M_TGT];
    __shared__ float s_tgval[FPB][M_TGT];
    __shared__ float s_pl1[FPB][M_TGT], s_pgi[FPB][M_TGT], s_pnl[FPB][M_TGT];
    __shared__ int   s_islast;
    __shared__ float s_w[3][2];

    // ---- stage A: targets + preds ----
    if (t < M_TGT) {
        const float4 t4 = ((const float4*)tb)[(size_t)f * M_TGT + t];
        float cx = t4.x, cy = t4.y, w = t4.z, h = t4.w;
        s_tgt[fl][t][0] = cx; s_tgt[fl][t][1] = cy; s_tgt[fl][t][2] = w; s_tgt[fl][t][3] = h;
        float x0 = cx - 0.5f * w, y0 = cy - 0.5f * h;
        float x1 = cx + 0.5f * w, y1 = cy + 0.5f * h;
        s_tgt[fl][t][4] = x0; s_tgt[fl][t][5] = y0; s_tgt[fl][t][6] = x1; s_tgt[fl][t][7] = y1;
        s_tgt[fl][t][8] = (x1 - x0) * (y1 - y0);
        s_lab[fl][t] = labels[f * M_TGT + t];
        s_tid[fl][t] = tids[f * M_TGT + t];
    }
    for (int j = t; j < N_PRED; j += 256) s_claim[fl][j] = 0x7fffffff;

    float p0[2], p1[2], pcx[2], pcy[2], pw[2], ph[2];
    float px0[2], py0[2], px1[2], py1[2], parea[2];
#pragma unroll
    for (int c = 0; c < 2; ++c) {
        int j = t + c * 256;
        p0[c] = p1[c] = pcx[c] = pcy[c] = pw[c] = ph[c] = 0.f;
        px0[c] = py0[c] = px1[c] = py1[c] = parea[c] = 0.f;
        if (j < N_PRED) {
            float2 lg = ((const float2*)pl)[(size_t)f * N_PRED + j];
            float mx  = fmaxf(lg.x, lg.y);
            float e0  = expf(lg.x - mx), e1 = expf(lg.y - mx);
            float inv = 1.0f / (e0 + e1);
            p0[c] = e0 * inv; p1[c] = e1 * inv;
            float4 b4 = ((const float4*)pb)[(size_t)f * N_PRED + j];
            pcx[c] = b4.x; pcy[c] = b4.y; pw[c] = b4.z; ph[c] = b4.w;
            s_pbox[fl][j][0] = b4.x; s_pbox[fl][j][1] = b4.y;
            s_pbox[fl][j][2] = b4.z; s_pbox[fl][j][3] = b4.w;
            px0[c] = b4.x - 0.5f * b4.z; py0[c] = b4.y - 0.5f * b4.w;
            px1[c] = b4.x + 0.5f * b4.z; py1[c] = b4.y + 0.5f * b4.w;
            parea[c] = (px1[c] - px0[c]) * (py1[c] - py0[c]);
        }
    }
    __syncthreads();

    // cost fill (fp16): C[m][j] = 2*(-prob[label]) + 5*L1 - 2*giou
    for (int m = 0; m < M_TGT; ++m) {
        float tcx = s_tgt[fl][m][0], tcy = s_tgt[fl][m][1], tw = s_tgt[fl][m][2], th = s_tgt[fl][m][3];
        float tx0 = s_tgt[fl][m][4], ty0 = s_tgt[fl][m][5], tx1 = s_tgt[fl][m][6], ty1 = s_tgt[fl][m][7];
        float ta  = s_tgt[fl][m][8];
        int   lab = s_lab[fl][m];
#pragma unroll
        for (int c = 0; c < 2; ++c) {
            int j = t + c * 256;
            if (j < N_PRED) {
                float ccls = -((lab == 0) ? p0[c] : p1[c]);
                float cl1  = fabsf(pcx[c] - tcx) + fabsf(pcy[c] - tcy)
                           + fabsf(pw[c] - tw)  + fabsf(ph[c] - th);
                float ltx = fmaxf(px0[c], tx0), lty = fmaxf(py0[c], ty0);
                float rbx = fminf(px1[c], tx1), rby = fminf(py1[c], ty1);
                float iw = fmaxf(rbx - ltx, 0.f), ih = fmaxf(rby - lty, 0.f);
                float inter = iw * ih;
                float uni   = parea[c] + ta - inter;
                float iou   = inter / uni;
                float Ltx = fminf(px0[c], tx0), Lty = fminf(py0[c], ty0);
                float Rbx = fmaxf(px1[c], tx1), Rby = fmaxf(py1[c], ty1);
                float cw = fmaxf(Rbx - Ltx, 0.f), ch = fmaxf(Rby - Lty, 0.f);
                float ac = cw * ch;
                float giou = iou - (ac - uni) / ac;
                s_cost[fl][m * PITCH + j] = (f16)(2.f * ccls + 5.f * cl1 - 2.f * giou);
            }
        }
    }
    __syncthreads();

    // greedy init: row minima, 8 threads per row
    {
        int m = t >> 3, k = t & 7;
        float bv = INFINITY; int bj = 0;
        const f16* crow = s_cost[fl] + m * PITCH;
        for (int j = k; j < N_PRED; j += 8) {
            float c = (float)crow[j];
            if (c < bv) { bv = c; bj = j; }
        }
#pragma unroll
        for (int off = 1; off < 8; off <<= 1) {
            float ov = __shfl_xor(bv, off);
            int   oj = __shfl_xor(bj, off);
            if (ov < bv || (ov == bv && oj < bj)) { bv = ov; bj = oj; }
        }
        if (k == 0) {
            s_rowval[fl][m] = bv;
            s_rowarg[fl][m] = bj;
            atomicMin(&s_claim[fl][bj], m);
        }
    }
    __syncthreads();

    // ---- stage B: solver wave (w4==0) overlapped with speculative LSE ----
    if (w4 == 0) {
        int pcol[NSLOT];
#pragma unroll
        for (int s = 0; s < NSLOT; ++s) {
            int j = s * 64 + lane;
            pcol[s] = -1;
            if (j < N_PRED) { int c = s_claim[fl][j]; if (c != 0x7fffffff) pcol[s] = c; }
        }
        float v[NSLOT];
#pragma unroll
        for (int s = 0; s < NSLOT; ++s) v[s] = 0.f;

        float u_reg = 0.f;
        bool assigned = false;
        if (lane < M_TGT) {
            u_reg = s_rowval[fl][lane];
            assigned = (s_claim[fl][s_rowarg[fl][lane]] == lane);
        }
        unsigned freeMask = ~(unsigned)(__ballot(assigned) & 0xFFFFFFFFull);

        while (freeMask) {
            int i = __ffs(freeMask) - 1;
            freeMask &= freeMask - 1;

            float minv[NSLOT]; int way[NSLOT]; int used[NSLOT];
#pragma unroll
            for (int s = 0; s < NSLOT; ++s) { minv[s] = INFINITY; way[s] = -1; used[s] = 0; }
            unsigned treeMask = 0;
            int i0 = i, j0 = -1;

            for (int guard = 0; guard < 4096; ++guard) {
                treeMask |= 1u << i0;
                float u_i0 = __shfl(u_reg, i0);
                const f16* crow2 = s_cost[fl] + i0 * PITCH;
                unsigned bkey = 0xFFFFFFFFu;
#pragma unroll
                for (int s = 0; s < NSLOT; ++s) {
                    int j = s * 64 + lane;
                    if (j < N_PRED && !used[s]) {
                        float cur = (float)crow2[j] - u_i0 - v[s];
                        if (cur < minv[s]) { minv[s] = cur; way[s] = j0; }
                        unsigned key = (mono32(minv[s]) & 0xFFFFFE00u) | (unsigned)j;
                        bkey = min(bkey, key);
                    }
                }
#pragma unroll
                for (int off = 32; off > 0; off >>= 1)
                    bkey = min(bkey, (unsigned)__shfl_xor((int)bkey, off));
                int j1 = bkey & 0x1FF;
                int slot1 = j1 >> 6, lane1 = j1 & 63;
                float delta = __shfl(sel5f(minv, slot1), lane1);

                if (lane < M_TGT && ((treeMask >> lane) & 1)) u_reg += delta;
#pragma unroll
                for (int s = 0; s < NSLOT; ++s) {
                    int j = s * 64 + lane;
                    if (j < N_PRED) { if (used[s]) v[s] -= delta; else minv[s] -= delta; }
                }
                int pj1 = __shfl(sel5i(pcol, slot1), lane1);
                if (lane == lane1) set5i(used, slot1, 1);
                j0 = j1;
                if (pj1 < 0) break;
                i0 = pj1;
            }
            int j = j0;
            while (true) {
                int slot = j >> 6, ln = j & 63;
                int wj = __shfl(sel5i(way, slot), ln);
                int newp = (wj < 0) ? i : __shfl(sel5i(pcol, wj >> 6), wj & 63);
                if (lane == ln) set5i(pcol, slot, newp);
                if (wj < 0) break;
                j = wj;
            }
        }
#pragma unroll
        for (int s = 0; s < NSLOT; ++s) {
            int j = s * 64 + lane;
            if (j < N_PRED && pcol[s] >= 0) s_col4row[fl][pcol[s]] = j;
        }
    } else {
        // speculative LSE for greedy-claimed columns (3 waves per frame)
        for (int m = w4 - 1; m < M_TGT; m += 3) {
            int col = s_rowarg[fl][m];
            const float* base = il + ((size_t)f * N_PRED + col) * K_ID;
            const float4* b4 = (const float4*)base;
            float4 x0 = b4[lane];
            float4 x1 = b4[64 + lane];
            float mx = fmaxf(fmaxf(fmaxf(x0.x, x0.y), fmaxf(x0.z, x0.w)),
                             fmaxf(fmaxf(x1.x, x1.y), fmaxf(x1.z, x1.w)));
#pragma unroll
            for (int off = 32; off > 0; off >>= 1) mx = fmaxf(mx, __shfl_xor(mx, off));
            float se = expf(x0.x - mx) + expf(x0.y - mx) + expf(x0.z - mx) + expf(x0.w - mx)
                     + expf(x1.x - mx) + expf(x1.y - mx) + expf(x1.z - mx) + expf(x1.w - mx);
#pragma unroll
            for (int off = 32; off > 0; off >>= 1) se += __shfl_xor(se, off);
            if (lane == 0) {
                s_lse[fl][m]   = mx + logf(se);
                s_tgval[fl][m] = base[s_tid[fl][m]];
            }
        }
    }
    __syncthreads();

    // ---- stage C: pair losses (8 threads/pair), reuse speculative LSE ----
    {
        const int m = t >> 3, k = t & 7;
        const int idx = s_col4row[fl][m];
        const bool match = (idx == s_rowarg[fl][m]);
        float lse = s_lse[fl][m], tgval = s_tgval[fl][m];

        if (!match) {   // recompute LSE for changed rows (~2/frame)
            const float* base = il + ((size_t)f * N_PRED + idx) * K_ID;
            const float4* b4 = (const float4*)base + k * 16;
            float4 c0[8];
#pragma unroll
            for (int q = 0; q < 8; ++q) c0[q] = b4[q];
            float m1 = -INFINITY;
#pragma unroll
            for (int q = 0; q < 8; ++q)
                m1 = fmaxf(m1, fmaxf(fmaxf(c0[q].x, c0[q].y), fmaxf(c0[q].z, c0[q].w)));
            float s1 = 0.f;
#pragma unroll
            for (int q = 0; q < 8; ++q)
                s1 += expf(c0[q].x - m1) + expf(c0[q].y - m1) + expf(c0[q].z - m1) + expf(c0[q].w - m1);
#pragma unroll
            for (int q = 0; q < 8; ++q) c0[q] = b4[8 + q];
            float m2 = -INFINITY;
#pragma unroll
            for (int q = 0; q < 8; ++q)
                m2 = fmaxf(m2, fmaxf(fmaxf(c0[q].x, c0[q].y), fmaxf(c0[q].z, c0[q].w)));
            float s2 = 0.f;
#pragma unroll
            for (int q = 0; q < 8; ++q)
                s2 += expf(c0[q].x - m2) + expf(c0[q].y - m2) + expf(c0[q].z - m2) + expf(c0[q].w - m2);
            float M = fmaxf(m1, m2);
            float S = s1 * expf(m1 - M) + s2 * expf(m2 - M);
#pragma unroll
            for (int off = 1; off < 8; off <<= 1) {
                float oM = __shfl_xor(M, off);
                float oS = __shfl_xor(S, off);
                float Mn = fmaxf(M, oM);
                S = S * expf(M - Mn) + oS * expf(oM - Mn);
                M = Mn;
            }
            lse = M + logf(S);
            if (k == 0) tgval = base[s_tid[fl][m]];
        }

        if (k == 0) {
            float nll = lse - tgval;
            float bcx = s_pbox[fl][idx][0], bcy = s_pbox[fl][idx][1];
            float bw  = s_pbox[fl][idx][2], bh  = s_pbox[fl][idx][3];
            float tcx = s_tgt[fl][m][0], tcy = s_tgt[fl][m][1], tw = s_tgt[fl][m][2], th = s_tgt[fl][m][3];
            float l1 = fabsf(bcx - tcx) + fabsf(bcy - tcy) + fabsf(bw - tw) + fabsf(bh - th);
            float ax0 = bcx - 0.5f * bw, ay0 = bcy - 0.5f * bh;
            float ax1 = bcx + 0.5f * bw, ay1 = bcy + 0.5f * bh;
            float tx0 = s_tgt[fl][m][4], ty0 = s_tgt[fl][m][5], tx1 = s_tgt[fl][m][6], ty1 = s_tgt[fl][m][7];
            float a1 = (ax1 - ax0) * (ay1 - ay0);
            float a2 = s_tgt[fl][m][8];
            float iw = fmaxf(fminf(ax1, tx1) - fmaxf(ax0, tx0), 0.f);
            float ih = fmaxf(fminf(ay1, ty1) - fmaxf(ay0, ty0), 0.f);
            float inter = iw * ih;
            float uni = a1 + a2 - inter;
            float iou = inter / uni;
            float cw = fmaxf(fmaxf(ax1, tx1) - fminf(ax0, tx0), 0.f);
            float ch = fmaxf(fmaxf(ay1, ty1) - fminf(ay0, ty0), 0.f);
            float ac = cw * ch;
            float giou = iou - (ac - uni) / ac;
            s_pl1[fl][m] = l1; s_pgi[fl][m] = giou; s_pnl[fl][m] = nll;
        }
    }
    __syncthreads();

    // ---- stage D: per-frame reduce, then last block finalizes ----
    if (w4 == 0) {
        float a = 0.f, b = 0.f, c = 0.f;
        if (lane < M_TGT) { a = s_pl1[fl][lane]; b = s_pgi[fl][lane]; c = s_pnl[fl][lane]; }
#pragma unroll
        for (int off = 32; off > 0; off >>= 1) {
            a += __shfl_xor(a, off);
            b += __shfl_xor(b, off);
            c += __shfl_xor(c, off);
        }
        if (lane == 0) {
            __hip_atomic_store(&frame_part[f * 4 + 0], a, __ATOMIC_RELAXED, __HIP_MEMORY_SCOPE_AGENT);
            __hip_atomic_store(&frame_part[f * 4 + 1], b, __ATOMIC_RELAXED, __HIP_MEMORY_SCOPE_AGENT);
            __hip_atomic_store(&frame_part[f * 4 + 2], c, __ATOMIC_RELAXED, __HIP_MEMORY_SCOPE_AGENT);
        }
    }
    __syncthreads();
    if (tid == 0) {
        __threadfence();
        int old = atomicAdd(counter, 1);
        s_islast = (old == NBLOCKS - 1) ? 1 : 0;
    }
    __syncthreads();

    if (s_islast) {
        __threadfence();
        float a = 0.f, b = 0.f, c = 0.f;
        if (tid < F_FRAMES) {
            a = __hip_atomic_load(&frame_part[tid * 4 + 0], __ATOMIC_RELAXED, __HIP_MEMORY_SCOPE_AGENT);
            b = __hip_atomic_load(&frame_part[tid * 4 + 1], __ATOMIC_RELAXED, __HIP_MEMORY_SCOPE_AGENT);
            c = __hip_atomic_load(&frame_part[tid * 4 + 2], __ATOMIC_RELAXED, __HIP_MEMORY_SCOPE_AGENT);
        }
#pragma unroll
        for (int off = 32; off > 0; off >>= 1) {
            a += __shfl_xor(a, off);
            b += __shfl_xor(b, off);
            c += __shfl_xor(c, off);
        }
        int wv = tid >> 6;
        if (lane == 0 && wv < 2) { s_w[0][wv] = a; s_w[1][wv] = b; s_w[2][wv] = c; }
        __syncthreads();
        if (tid == 0) {
            constexpr float P = (float)(F_FRAMES * M_TGT);
            float S0 = s_w[0][0] + s_w[0][1];
            float S1 = s_w[1][0] + s_w[1][1];
            float S2 = s_w[2][0] + s_w[2][1];
            float l1  = S0 / (P * 4.f);
            float gl  = 1.f - S1 / P;
            float idl = S2 / P;
            out[0] = 5.f * l1 + 2.f * gl + 1.f * idl;   // + 2*0 cls
            out[1] = 0.f;
            out[2] = l1;
            out[3] = gl;
            out[4] = idl;
        }
    }
}

extern "C" void kernel_launch(void* const* d_in, const int* in_sizes, int n_in,
                              void* d_out, int out_size, void* d_ws, size_t ws_size,
                              hipStream_t stream) {
    const float* pl     = (const float*)d_in[0];   // pred_logits  [8,16,300,2]
    const float* pb     = (const float*)d_in[1];   // pred_boxes   [8,16,300,4]
    const float* il     = (const float*)d_in[2];   // id_logits    [8,16,300,512]
    const int*   labels = (const int*)d_in[3];     // target_labels [128,32]
    const float* tb     = (const float*)d_in[4];   // target_boxes  [128,32,4]
    const int*   tids   = (const int*)d_in[5];     // target_ids    [128,32]
    float* out = (float*)d_out;

    float* frame_part = (float*)d_ws;                          // [128,4] = 2 KB
    int*   counter    = (int*)((char*)d_ws + 4096);            // 4 B

    hipMemsetAsync(counter, 0, sizeof(int), stream);
    motip_fused_kernel<<<NBLOCKS, 512, 0, stream>>>(
        pl, pb, il, labels, tb, tids, frame_part, counter, out);
}

// Round 7
// 156.303 us; speedup vs baseline: 1.0197x; 1.0197x over previous
//
#include <hip/hip_runtime.h>
#include <math.h>

// MOTIP criterion, single fused kernel (R5 config: 1 frame/block, 256 thr):
// cost + JV Hungarian + speculative pair losses overlapped with the solve +
// last-block global reduction. This round: spec-LSE software-pipelined
// (2 columns in flight) + single-exp softmax.
// F=128 frames, N=300 preds, M=32 targets, C=2 classes, K1=512 id classes.

constexpr int F_FRAMES = 128;
constexpr int N_PRED   = 300;
constexpr int M_TGT    = 32;
constexpr int K_ID     = 512;
constexpr int NSLOT    = 5;     // ceil(300/64) for the wave-0 solver
constexpr int PITCH    = 301;   // LDS row pitch

// ---------- 5-element register-array dynamic access ----------
__device__ __forceinline__ int sel5i(const int a[NSLOT], int s) {
    int r = a[0];
    r = (s == 1) ? a[1] : r;
    r = (s == 2) ? a[2] : r;
    r = (s == 3) ? a[3] : r;
    r = (s == 4) ? a[4] : r;
    return r;
}
__device__ __forceinline__ float sel5f(const float a[NSLOT], int s) {
    float r = a[0];
    r = (s == 1) ? a[1] : r;
    r = (s == 2) ? a[2] : r;
    r = (s == 3) ? a[3] : r;
    r = (s == 4) ? a[4] : r;
    return r;
}
__device__ __forceinline__ void set5i(int a[NSLOT], int s, int val) {
    if (s == 0) a[0] = val;
    if (s == 1) a[1] = val;
    if (s == 2) a[2] = val;
    if (s == 3) a[3] = val;
    if (s == 4) a[4] = val;
}
// monotone float -> uint (order-preserving)
__device__ __forceinline__ unsigned mono32(float x) {
    unsigned b = __float_as_uint(x);
    return b ^ ((b & 0x80000000u) ? 0xFFFFFFFFu : 0x80000000u);
}

__device__ __forceinline__ void lse_reduce(const float4& x0, const float4& x1,
                                           float& lse_out) {
    float mx = fmaxf(fmaxf(fmaxf(x0.x, x0.y), fmaxf(x0.z, x0.w)),
                     fmaxf(fmaxf(x1.x, x1.y), fmaxf(x1.z, x1.w)));
#pragma unroll
    for (int off = 32; off > 0; off >>= 1) mx = fmaxf(mx, __shfl_xor(mx, off));
    float se = expf(x0.x - mx) + expf(x0.y - mx) + expf(x0.z - mx) + expf(x0.w - mx)
             + expf(x1.x - mx) + expf(x1.y - mx) + expf(x1.z - mx) + expf(x1.w - mx);
#pragma unroll
    for (int off = 32; off > 0; off >>= 1) se += __shfl_xor(se, off);
    lse_out = mx + logf(se);
}

__global__ __launch_bounds__(256) void motip_fused_kernel(
    const float* __restrict__ pl,      // [F,N,2]
    const float* __restrict__ pb,      // [F,N,4]
    const float* __restrict__ il,      // [F,N,K]
    const int*   __restrict__ labels,  // [F,M]
    const float* __restrict__ tb,      // [F,M,4]
    const int*   __restrict__ tids,    // [F,M]
    float* __restrict__ frame_part,    // [F,4] in ws
    int*   __restrict__ counter,       // zeroed by memsetAsync
    float* __restrict__ out)           // [5]
{
    const int f    = blockIdx.x;
    const int tid  = threadIdx.x;
    const int lane = tid & 63;
    const int wave = tid >> 6;

    __shared__ float s_cost[M_TGT * PITCH];
    __shared__ float s_pbox[N_PRED][4];
    __shared__ int   s_claim[N_PRED];
    __shared__ float s_tgt[M_TGT][9];           // cx,cy,w,h,x0,y0,x1,y1,area
    __shared__ int   s_lab[M_TGT];
    __shared__ int   s_tid[M_TGT];
    __shared__ float s_rowval[M_TGT];
    __shared__ int   s_rowarg[M_TGT];
    __shared__ int   s_col4row[M_TGT];
    __shared__ float s_lse[M_TGT];
    __shared__ float s_tgval[M_TGT];
    __shared__ float s_pl1[M_TGT], s_pgi[M_TGT], s_pnl[M_TGT];
    __shared__ int   s_islast;

    // ---- stage A ----
    if (tid < M_TGT) {
        const float4 t4 = ((const float4*)tb)[(size_t)f * M_TGT + tid];
        float cx = t4.x, cy = t4.y, w = t4.z, h = t4.w;
        s_tgt[tid][0] = cx; s_tgt[tid][1] = cy; s_tgt[tid][2] = w; s_tgt[tid][3] = h;
        float x0 = cx - 0.5f * w, y0 = cy - 0.5f * h;
        float x1 = cx + 0.5f * w, y1 = cy + 0.5f * h;
        s_tgt[tid][4] = x0; s_tgt[tid][5] = y0; s_tgt[tid][6] = x1; s_tgt[tid][7] = y1;
        s_tgt[tid][8] = (x1 - x0) * (y1 - y0);
        s_lab[tid] = labels[f * M_TGT + tid];
        s_tid[tid] = tids[f * M_TGT + tid];
    }
    for (int j = tid; j < N_PRED; j += 256) s_claim[j] = 0x7fffffff;

    float p0[2], p1[2], pcx[2], pcy[2], pw[2], ph[2];
    float px0[2], py0[2], px1[2], py1[2], parea[2];
#pragma unroll
    for (int c = 0; c < 2; ++c) {
        int j = tid + c * 256;
        p0[c] = p1[c] = pcx[c] = pcy[c] = pw[c] = ph[c] = 0.f;
        px0[c] = py0[c] = px1[c] = py1[c] = parea[c] = 0.f;
        if (j < N_PRED) {
            float2 lg = ((const float2*)pl)[(size_t)f * N_PRED + j];
            // softmax(2) with one exp, matching max-subtracted reference
            float d  = lg.y - lg.x;
            float e  = expf(-fabsf(d));
            float r  = 1.0f / (1.0f + e);
            float pmax = r, pmin = e * r;
            p0[c] = (d <= 0.f) ? pmax : pmin;
            p1[c] = (d <= 0.f) ? pmin : pmax;
            float4 b4 = ((const float4*)pb)[(size_t)f * N_PRED + j];
            pcx[c] = b4.x; pcy[c] = b4.y; pw[c] = b4.z; ph[c] = b4.w;
            s_pbox[j][0] = b4.x; s_pbox[j][1] = b4.y; s_pbox[j][2] = b4.z; s_pbox[j][3] = b4.w;
            px0[c] = b4.x - 0.5f * b4.z; py0[c] = b4.y - 0.5f * b4.w;
            px1[c] = b4.x + 0.5f * b4.z; py1[c] = b4.y + 0.5f * b4.w;
            parea[c] = (px1[c] - px0[c]) * (py1[c] - py0[c]);
        }
    }
    __syncthreads();

    // cost fill: C[m][j] = 2*(-prob[label]) + 5*L1 - 2*giou
    for (int m = 0; m < M_TGT; ++m) {
        float tcx = s_tgt[m][0], tcy = s_tgt[m][1], tw = s_tgt[m][2], th = s_tgt[m][3];
        float tx0 = s_tgt[m][4], ty0 = s_tgt[m][5], tx1 = s_tgt[m][6], ty1 = s_tgt[m][7];
        float ta  = s_tgt[m][8];
        int   lab = s_lab[m];
#pragma unroll
        for (int c = 0; c < 2; ++c) {
            int j = tid + c * 256;
            if (j < N_PRED) {
                float ccls = -((lab == 0) ? p0[c] : p1[c]);
                float cl1  = fabsf(pcx[c] - tcx) + fabsf(pcy[c] - tcy)
                           + fabsf(pw[c] - tw)  + fabsf(ph[c] - th);
                float ltx = fmaxf(px0[c], tx0), lty = fmaxf(py0[c], ty0);
                float rbx = fminf(px1[c], tx1), rby = fminf(py1[c], ty1);
                float iw = fmaxf(rbx - ltx, 0.f), ih = fmaxf(rby - lty, 0.f);
                float inter = iw * ih;
                float uni   = parea[c] + ta - inter;
                float iou   = inter / uni;
                float Ltx = fminf(px0[c], tx0), Lty = fminf(py0[c], ty0);
                float Rbx = fmaxf(px1[c], tx1), Rby = fmaxf(py1[c], ty1);
                float cw = fmaxf(Rbx - Ltx, 0.f), ch = fmaxf(Rby - Lty, 0.f);
                float ac = cw * ch;
                float giou = iou - (ac - uni) / ac;
                s_cost[m * PITCH + j] = 2.f * ccls + 5.f * cl1 - 2.f * giou;
            }
        }
    }
    __syncthreads();

    // greedy init: row minima, 8 threads per row
    {
        int m = tid >> 3, k = tid & 7;
        float bv = INFINITY; int bj = 0;
        const float* crow = s_cost + m * PITCH;
        for (int j = k; j < N_PRED; j += 8) {
            float c = crow[j];
            if (c < bv) { bv = c; bj = j; }
        }
#pragma unroll
        for (int off = 1; off < 8; off <<= 1) {
            float ov = __shfl_xor(bv, off);
            int   oj = __shfl_xor(bj, off);
            if (ov < bv || (ov == bv && oj < bj)) { bv = ov; bj = oj; }
        }
        if (k == 0) {
            s_rowval[m] = bv;
            s_rowarg[m] = bj;
            atomicMin(&s_claim[bj], m);
        }
    }
    __syncthreads();

    // ---- stage B: solver (wave 0) overlapped with pipelined spec-LSE ----
    if (wave == 0) {
        int pcol[NSLOT];
#pragma unroll
        for (int s = 0; s < NSLOT; ++s) {
            int j = s * 64 + lane;
            pcol[s] = -1;
            if (j < N_PRED) { int c = s_claim[j]; if (c != 0x7fffffff) pcol[s] = c; }
        }
        float v[NSLOT];
#pragma unroll
        for (int s = 0; s < NSLOT; ++s) v[s] = 0.f;

        float u_reg = 0.f;
        bool assigned = false;
        if (lane < M_TGT) {
            u_reg = s_rowval[lane];
            assigned = (s_claim[s_rowarg[lane]] == lane);
        }
        unsigned freeMask = ~(unsigned)(__ballot(assigned) & 0xFFFFFFFFull);

        while (freeMask) {
            int i = __ffs(freeMask) - 1;
            freeMask &= freeMask - 1;

            float minv[NSLOT]; int way[NSLOT]; int used[NSLOT];
#pragma unroll
            for (int s = 0; s < NSLOT; ++s) { minv[s] = INFINITY; way[s] = -1; used[s] = 0; }
            unsigned treeMask = 0;
            int i0 = i, j0 = -1;

            for (int guard = 0; guard < 4096; ++guard) {
                treeMask |= 1u << i0;
                float u_i0 = __shfl(u_reg, i0);
                const float* crow2 = s_cost + i0 * PITCH;
                unsigned bkey = 0xFFFFFFFFu;
#pragma unroll
                for (int s = 0; s < NSLOT; ++s) {
                    int j = s * 64 + lane;
                    if (j < N_PRED && !used[s]) {
                        float cur = crow2[j] - u_i0 - v[s];
                        if (cur < minv[s]) { minv[s] = cur; way[s] = j0; }
                        unsigned key = (mono32(minv[s]) & 0xFFFFFE00u) | (unsigned)j;
                        bkey = min(bkey, key);
                    }
                }
#pragma unroll
                for (int off = 32; off > 0; off >>= 1)
                    bkey = min(bkey, (unsigned)__shfl_xor((int)bkey, off));
                int j1 = bkey & 0x1FF;
                int slot1 = j1 >> 6, lane1 = j1 & 63;
                float delta = __shfl(sel5f(minv, slot1), lane1);

                if (lane < M_TGT && ((treeMask >> lane) & 1)) u_reg += delta;
#pragma unroll
                for (int s = 0; s < NSLOT; ++s) {
                    int j = s * 64 + lane;
                    if (j < N_PRED) { if (used[s]) v[s] -= delta; else minv[s] -= delta; }
                }
                int pj1 = __shfl(sel5i(pcol, slot1), lane1);
                if (lane == lane1) set5i(used, slot1, 1);
                j0 = j1;
                if (pj1 < 0) break;
                i0 = pj1;
            }
            int j = j0;
            while (true) {
                int slot = j >> 6, ln = j & 63;
                int wj = __shfl(sel5i(way, slot), ln);
                int newp = (wj < 0) ? i : __shfl(sel5i(pcol, wj >> 6), wj & 63);
                if (lane == ln) set5i(pcol, slot, newp);
                if (wj < 0) break;
                j = wj;
            }
        }
#pragma unroll
        for (int s = 0; s < NSLOT; ++s) {
            int j = s * 64 + lane;
            if (j < N_PRED && pcol[s] >= 0) s_col4row[pcol[s]] = j;
        }
    } else {
        // waves 1-3: speculative LSE, 2 columns in flight per iteration
        const int base_m = wave - 1;
        const int total  = (35 - wave) / 3;   // 11,11,10 for waves 1,2,3
        for (int it = 0; it < total; it += 2) {
            int ma = base_m + 3 * it;
            bool hasB = (it + 1) < total;
            int mb = hasB ? (ma + 3) : ma;

            const float* baseA = il + ((size_t)f * N_PRED + s_rowarg[ma]) * K_ID;
            const float4* A4 = (const float4*)baseA;
            float4 a0 = A4[lane];
            float4 a1 = A4[64 + lane];
            float tga = baseA[s_tid[ma]];

            const float* baseB = il + ((size_t)f * N_PRED + s_rowarg[mb]) * K_ID;
            const float4* B4 = (const float4*)baseB;
            float4 b0, b1; float tgb = 0.f;
            if (hasB) {
                b0 = B4[lane];
                b1 = B4[64 + lane];
                tgb = baseB[s_tid[mb]];
            }

            float lseA;
            lse_reduce(a0, a1, lseA);
            if (lane == 0) { s_lse[ma] = lseA; s_tgval[ma] = tga; }

            if (hasB) {
                float lseB;
                lse_reduce(b0, b1, lseB);
                if (lane == 0) { s_lse[mb] = lseB; s_tgval[mb] = tgb; }
            }
        }
    }
    __syncthreads();

    // ---- stage C: pair losses (8 threads/pair), reuse speculative LSE ----
    {
        const int m = tid >> 3, k = tid & 7;
        const int idx = s_col4row[m];
        const bool match = (idx == s_rowarg[m]);
        float lse = s_lse[m], tgval = s_tgval[m];

        if (!match) {   // recompute LSE for changed rows (~2/frame)
            const float* base = il + ((size_t)f * N_PRED + idx) * K_ID;
            const float4* b4 = (const float4*)base + k * 16;
            float4 c0[8];
#pragma unroll
            for (int q = 0; q < 8; ++q) c0[q] = b4[q];
            float m1 = -INFINITY;
#pragma unroll
            for (int q = 0; q < 8; ++q)
                m1 = fmaxf(m1, fmaxf(fmaxf(c0[q].x, c0[q].y), fmaxf(c0[q].z, c0[q].w)));
            float s1 = 0.f;
#pragma unroll
            for (int q = 0; q < 8; ++q)
                s1 += expf(c0[q].x - m1) + expf(c0[q].y - m1) + expf(c0[q].z - m1) + expf(c0[q].w - m1);
#pragma unroll
            for (int q = 0; q < 8; ++q) c0[q] = b4[8 + q];
            float m2 = -INFINITY;
#pragma unroll
            for (int q = 0; q < 8; ++q)
                m2 = fmaxf(m2, fmaxf(fmaxf(c0[q].x, c0[q].y), fmaxf(c0[q].z, c0[q].w)));
            float s2 = 0.f;
#pragma unroll
            for (int q = 0; q < 8; ++q)
                s2 += expf(c0[q].x - m2) + expf(c0[q].y - m2) + expf(c0[q].z - m2) + expf(c0[q].w - m2);
            float M = fmaxf(m1, m2);
            float S = s1 * expf(m1 - M) + s2 * expf(m2 - M);
#pragma unroll
            for (int off = 1; off < 8; off <<= 1) {
                float oM = __shfl_xor(M, off);
                float oS = __shfl_xor(S, off);
                float Mn = fmaxf(M, oM);
                S = S * expf(M - Mn) + oS * expf(oM - Mn);
                M = Mn;
            }
            lse = M + logf(S);
            if (k == 0) tgval = base[s_tid[m]];
        }

        if (k == 0) {
            float nll = lse - tgval;
            float bcx = s_pbox[idx][0], bcy = s_pbox[idx][1];
            float bw  = s_pbox[idx][2], bh  = s_pbox[idx][3];
            float tcx = s_tgt[m][0], tcy = s_tgt[m][1], tw = s_tgt[m][2], th = s_tgt[m][3];
            float l1 = fabsf(bcx - tcx) + fabsf(bcy - tcy) + fabsf(bw - tw) + fabsf(bh - th);
            float ax0 = bcx - 0.5f * bw, ay0 = bcy - 0.5f * bh;
            float ax1 = bcx + 0.5f * bw, ay1 = bcy + 0.5f * bh;
            float tx0 = s_tgt[m][4], ty0 = s_tgt[m][5], tx1 = s_tgt[m][6], ty1 = s_tgt[m][7];
            float a1 = (ax1 - ax0) * (ay1 - ay0);
            float a2 = s_tgt[m][8];
            float iw = fmaxf(fminf(ax1, tx1) - fmaxf(ax0, tx0), 0.f);
            float ih = fmaxf(fminf(ay1, ty1) - fmaxf(ay0, ty0), 0.f);
            float inter = iw * ih;
            float uni = a1 + a2 - inter;
            float iou = inter / uni;
            float cw = fmaxf(fmaxf(ax1, tx1) - fminf(ax0, tx0), 0.f);
            float ch = fmaxf(fmaxf(ay1, ty1) - fminf(ay0, ty0), 0.f);
            float ac = cw * ch;
            float giou = iou - (ac - uni) / ac;
            s_pl1[m] = l1; s_pgi[m] = giou; s_pnl[m] = nll;
        }
    }
    __syncthreads();

    // ---- stage D: per-frame reduce, release-store, last block finalizes ----
    if (wave == 0) {
        float a = 0.f, b = 0.f, c = 0.f;
        if (lane < M_TGT) { a = s_pl1[lane]; b = s_pgi[lane]; c = s_pnl[lane]; }
#pragma unroll
        for (int off = 32; off > 0; off >>= 1) {
            a += __shfl_xor(a, off);
            b += __shfl_xor(b, off);
            c += __shfl_xor(c, off);
        }
        if (lane == 0) {
            __hip_atomic_store(&frame_part[f * 4 + 0], a, __ATOMIC_RELAXED, __HIP_MEMORY_SCOPE_AGENT);
            __hip_atomic_store(&frame_part[f * 4 + 1], b, __ATOMIC_RELAXED, __HIP_MEMORY_SCOPE_AGENT);
            __hip_atomic_store(&frame_part[f * 4 + 2], c, __ATOMIC_RELAXED, __HIP_MEMORY_SCOPE_AGENT);
            __threadfence();
            int old = atomicAdd(counter, 1);
            s_islast = (old == F_FRAMES - 1) ? 1 : 0;
        }
    }
    __syncthreads();

    if (s_islast) {
        __threadfence();
        float a = 0.f, b = 0.f, c = 0.f;
        if (tid < F_FRAMES) {
            a = __hip_atomic_load(&frame_part[tid * 4 + 0], __ATOMIC_RELAXED, __HIP_MEMORY_SCOPE_AGENT);
            b = __hip_atomic_load(&frame_part[tid * 4 + 1], __ATOMIC_RELAXED, __HIP_MEMORY_SCOPE_AGENT);
            c = __hip_atomic_load(&frame_part[tid * 4 + 2], __ATOMIC_RELAXED, __HIP_MEMORY_SCOPE_AGENT);
        }
#pragma unroll
        for (int off = 32; off > 0; off >>= 1) {
            a += __shfl_xor(a, off);
            b += __shfl_xor(b, off);
            c += __shfl_xor(c, off);
        }
        __shared__ float w[3][2];
        if (lane == 0 && wave < 2) { w[0][wave] = a; w[1][wave] = b; w[2][wave] = c; }
        __syncthreads();
        if (tid == 0) {
            constexpr float P = (float)(F_FRAMES * M_TGT);
            float S0 = w[0][0] + w[0][1];
            float S1 = w[1][0] + w[1][1];
            float S2 = w[2][0] + w[2][1];
            float l1  = S0 / (P * 4.f);
            float gl  = 1.f - S1 / P;
            float idl = S2 / P;
            out[0] = 5.f * l1 + 2.f * gl + 1.f * idl;   // + 2*0 cls
            out[1] = 0.f;
            out[2] = l1;
            out[3] = gl;
            out[4] = idl;
        }
    }
}

extern "C" void kernel_launch(void* const* d_in, const int* in_sizes, int n_in,
                              void* d_out, int out_size, void* d_ws, size_t ws_size,
                              hipStream_t stream) {
    const float* pl     = (const float*)d_in[0];   // pred_logits  [8,16,300,2]
    const float* pb     = (const float*)d_in[1];   // pred_boxes   [8,16,300,4]
    const float* il     = (const float*)d_in[2];   // id_logits    [8,16,300,512]
    const int*   labels = (const int*)d_in[3];     // target_labels [128,32]
    const float* tb     = (const float*)d_in[4];   // target_boxes  [128,32,4]
    const int*   tids   = (const int*)d_in[5];     // target_ids    [128,32]
    float* out = (float*)d_out;

    float* frame_part = (float*)d_ws;                          // [128,4] = 2 KB
    int*   counter    = (int*)((char*)d_ws + 4096);            // 4 B

    hipMemsetAsync(counter, 0, sizeof(int), stream);
    motip_fused_kernel<<<F_FRAMES, 256, 0, stream>>>(
        pl, pb, il, labels, tb, tids, frame_part, counter, out);
}